// Round 1
// baseline (741.049 us; speedup 1.0000x reference)
//
#include <hip/hip_runtime.h>

// mLSTM  S=256 B=64 F=H=512 L=4
// v7: gemm rebuilt as 256x256 tile, BK=64, 8 waves, phase-interleaved schedule
//     with counted vmcnt (never drains to 0 in the loop), raw s_barrier,
//     setprio around MFMA clusters, XCD-aware block swizzle, and
//     fragment-order LDS (all LDS traffic is contiguous 1024B blocks -> 0 bank conflicts).
//   gemm_k  : Z = A @ W^T + bias (bf16 MFMA 16x16x32, 256x256 tile, BK=64)
//   stats_k : LN mu/rstd for gates 1-4 + sum_k
//   scanA_k : chunk-local scans (16-step), P_t = prod f stored
//   scanB_k : exact fp32 cross-chunk combine -> n0/chunk
//   normh_k : inline stats for q,o; n_t = n_loc + P_t*n0; ||n||; h = o*tanh(q*n_hat)+res

typedef unsigned short u16;
typedef unsigned int   u32;
typedef short s8v __attribute__((ext_vector_type(8)));   // 8 x bf16 (4 VGPRs)
typedef float f4v __attribute__((ext_vector_type(4)));   // 16x16 MFMA accum

#define S_    256
#define B_    64
#define F_    512
#define H_    512
#define L_    4
#define NG    3072          // 6*H
#define RALL  16384         // S*B
#define CH    16            // scan chunk length
#define INV_SQRT_H 0.044194173824159216f

__device__ __forceinline__ float bu2f(u16 u) {
    union { u32 i; float f; } z; z.i = ((u32)u) << 16; return z.f;
}
__device__ __forceinline__ u16 f2bf(float f) {
    union { float f; u32 i; } z; z.f = f;
    u32 r = (z.i + 0x7FFFu + ((z.i >> 16) & 1u)) >> 16;
    return (u16)r;
}
__device__ __forceinline__ float sigm(float x)  { return 1.0f / (1.0f + __expf(-x)); }
__device__ __forceinline__ float tanhf_(float x){ return 2.0f / (1.0f + __expf(-2.0f * x)) - 1.0f; }
__device__ __forceinline__ float wred64(float v) {
    #pragma unroll
    for (int m = 1; m < 64; m <<= 1) v += __shfl_xor(v, m);
    return v;
}
__device__ __forceinline__ void gl_lds16(const u16* g, u16* l) {
    __builtin_amdgcn_global_load_lds((const __attribute__((address_space(1))) u32*)g,
                                     (__attribute__((address_space(3))) u32*)l, 16, 0, 0);
}
__device__ __forceinline__ void unp8(uint4 u, float* f) {
    f[0] = bu2f((u16)(u.x & 0xffff)); f[1] = bu2f((u16)(u.x >> 16));
    f[2] = bu2f((u16)(u.y & 0xffff)); f[3] = bu2f((u16)(u.y >> 16));
    f[4] = bu2f((u16)(u.z & 0xffff)); f[5] = bu2f((u16)(u.z >> 16));
    f[6] = bu2f((u16)(u.w & 0xffff)); f[7] = bu2f((u16)(u.w >> 16));
}
__device__ __forceinline__ uint4 pck8(const float* f) {
    uint4 u;
    u.x = (u32)f2bf(f[0]) | ((u32)f2bf(f[1]) << 16);
    u.y = (u32)f2bf(f[2]) | ((u32)f2bf(f[3]) << 16);
    u.z = (u32)f2bf(f[4]) | ((u32)f2bf(f[5]) << 16);
    u.w = (u32)f2bf(f[6]) | ((u32)f2bf(f[7]) << 16);
    return u;
}

// ---- W [L,6,F,H] fp32 -> WT [L,6,H,F] bf16 (transpose via LDS tile) ----
__global__ void convw_k(const float* __restrict__ W, u16* __restrict__ WT) {
    __shared__ float tile[32][33];
    const int lg = blockIdx.z;                  // 0..23
    const int h0 = blockIdx.x * 32, f0 = blockIdx.y * 32;
    const float* Wb = W  + (size_t)lg * F_ * H_;
    u16*        WTb = WT + (size_t)lg * F_ * H_;
    const int tx = threadIdx.x, ty = threadIdx.y;  // 32x8
    #pragma unroll
    for (int i = 0; i < 32; i += 8)
        tile[ty + i][tx] = Wb[(size_t)(f0 + ty + i) * H_ + h0 + tx];
    __syncthreads();
    #pragma unroll
    for (int i = 0; i < 32; i += 8)
        WTb[(size_t)(h0 + ty + i) * F_ + f0 + tx] = f2bf(tile[tx][ty + i]);
}

// ---- x fp32 -> A bf16 ----
__global__ void convx_k(const float* __restrict__ x, u16* __restrict__ A) {
    const int i = blockIdx.x * 256 + threadIdx.x;   // covers RALL*F/4 exactly
    float4 v = ((const float4*)x)[i];
    u32 lo = (u32)f2bf(v.x) | ((u32)f2bf(v.y) << 16);
    u32 hi = (u32)f2bf(v.z) | ((u32)f2bf(v.w) << 16);
    ((uint2*)A)[i] = make_uint2(lo, hi);
}

// ---- GEMM: Z[m,3072] = A @ WT^T + bias.
// 256x256 tile, BK=64, 8 waves (2M x 4N), 16x16x32 MFMA, fragment-order LDS.
// LDS: lsA/lsB [dbuf][kstep][frag(16)][lane-slot 512 u16] = 64KB each (128KB total).
// Each gl_lds wave-call writes exactly one contiguous 1024B fragment block; the
// per-lane GLOBAL address performs the fragment gather (row = f*16+(l&15),
// kchunk = l>>4). Every ds_read_b128 is base + lane*16B -> conflict-free.
// Schedule per K-tile (4 phases = (kstep, n-half)); staging one K-tile ahead,
// one region (A-ks or B-ks of next tile) per phase; vmcnt(4) at end of odd
// phases forces exactly the regions needed 2 phases later, always leaving
// 2 regions (4 loads) in flight.
__global__ __launch_bounds__(512, 2) void gemm_k(const u16* __restrict__ A,
                                                 const u16* __restrict__ BT,
                                                 u16* __restrict__ Z,
                                                 const float* __restrict__ bias,
                                                 int arow0) {
    __shared__ __align__(16) u16 lsA[2][2][16][512];
    __shared__ __align__(16) u16 lsB[2][2][16][512];

    // XCD-aware swizzle: 12 consecutive ntiles of one mtile per XCD chunk.
    const int bid = blockIdx.x, nwg = gridDim.x;
    const int cpx = nwg >> 3;                       // nwg is always a multiple of 8
    const int swz = (bid & 7) * cpx + (bid >> 3);
    const int ntile = swz % 12, mtile = swz / 12;
    const int ncol0 = ntile * 256;

    const int t = threadIdx.x;
    const int lane = t & 63, wv = t >> 6;
    const int l15 = lane & 15, l4 = lane >> 4;
    const int lane8 = lane << 3;
    const int wm = (wv >> 2) * 8;                   // mfrag base (0 or 8)
    const int wn = (wv & 3) * 4;                    // nfrag base (0,4,8,12)

    const u16* Ab  = A  + (size_t)(arow0 + mtile * 256) * F_;
    const u16* Bb  = BT + (size_t)ncol0 * F_;
    const u16* gA0 = Ab + (size_t)(wv * 16 + l15) * F_ + l4 * 8;   // frag wv
    const u16* gA1 = gA0 + (size_t)128 * F_;                       // frag 8+wv
    const u16* gB0 = Bb + (size_t)(wv * 16 + l15) * F_ + l4 * 8;
    const u16* gB1 = gB0 + (size_t)128 * F_;

    f4v acc[8][4];
    #pragma unroll
    for (int m = 0; m < 8; ++m)
        #pragma unroll
        for (int n = 0; n < 4; ++n) acc[m][n] = 0.0f;

    auto stA = [&](int db, int ks, int kb) {
        const int ko = kb * 64 + ks * 32;
        gl_lds16(gA0 + ko, &lsA[db][ks][wv][lane8]);
        gl_lds16(gA1 + ko, &lsA[db][ks][8 + wv][lane8]);
    };
    auto stB = [&](int db, int ks, int kb) {
        const int ko = kb * 64 + ks * 32;
        gl_lds16(gB0 + ko, &lsB[db][ks][wv][lane8]);
        gl_lds16(gB1 + ko, &lsB[db][ks][8 + wv][lane8]);
    };

    // prologue: tile 0 fully issued; force A-ks0/B-ks0, leave A-ks1/B-ks1 in flight
    stA(0, 0, 0); stB(0, 0, 0); stA(0, 1, 0); stB(0, 1, 0);
    asm volatile("s_waitcnt vmcnt(4)" ::: "memory");
    __builtin_amdgcn_s_barrier();
    asm volatile("" ::: "memory");

    s8v fa[8], fb[2];
    #pragma unroll 2
    for (int kt = 0; kt < 8; ++kt) {
        const int d = kt & 1, dn = d ^ 1;
        const int kn = (kt < 7) ? kt + 1 : 7;       // kt=7: harmless dummy re-stage

        // ---- phase 0: ks=0, n-half 0; stage next A-ks0 ----
        #pragma unroll
        for (int m = 0; m < 8; ++m) fa[m] = *(const s8v*)&lsA[d][0][wm + m][lane8];
        fb[0] = *(const s8v*)&lsB[d][0][wn + 0][lane8];
        fb[1] = *(const s8v*)&lsB[d][0][wn + 1][lane8];
        stA(dn, 0, kn);
        asm volatile("" ::: "memory");
        __builtin_amdgcn_s_barrier();
        asm volatile("s_waitcnt lgkmcnt(0)" ::: "memory");
        __builtin_amdgcn_sched_barrier(0);
        __builtin_amdgcn_s_setprio(1);
        #pragma unroll
        for (int m = 0; m < 8; ++m) {
            acc[m][0] = __builtin_amdgcn_mfma_f32_16x16x32_bf16(fa[m], fb[0], acc[m][0], 0, 0, 0);
            acc[m][1] = __builtin_amdgcn_mfma_f32_16x16x32_bf16(fa[m], fb[1], acc[m][1], 0, 0, 0);
        }
        __builtin_amdgcn_s_setprio(0);
        asm volatile("" ::: "memory");
        __builtin_amdgcn_s_barrier();
        asm volatile("" ::: "memory");

        // ---- phase 1: ks=0, n-half 1; stage next B-ks0; force this tile's ks1 ----
        fb[0] = *(const s8v*)&lsB[d][0][wn + 2][lane8];
        fb[1] = *(const s8v*)&lsB[d][0][wn + 3][lane8];
        stB(dn, 0, kn);
        asm volatile("" ::: "memory");
        __builtin_amdgcn_s_barrier();
        asm volatile("s_waitcnt lgkmcnt(0)" ::: "memory");
        __builtin_amdgcn_sched_barrier(0);
        __builtin_amdgcn_s_setprio(1);
        #pragma unroll
        for (int m = 0; m < 8; ++m) {
            acc[m][2] = __builtin_amdgcn_mfma_f32_16x16x32_bf16(fa[m], fb[0], acc[m][2], 0, 0, 0);
            acc[m][3] = __builtin_amdgcn_mfma_f32_16x16x32_bf16(fa[m], fb[1], acc[m][3], 0, 0, 0);
        }
        __builtin_amdgcn_s_setprio(0);
        asm volatile("s_waitcnt vmcnt(4)" ::: "memory");   // forces [kt:A1],[kt:B1]
        __builtin_amdgcn_s_barrier();
        asm volatile("" ::: "memory");

        // ---- phase 2: ks=1, n-half 0; stage next A-ks1 ----
        #pragma unroll
        for (int m = 0; m < 8; ++m) fa[m] = *(const s8v*)&lsA[d][1][wm + m][lane8];
        fb[0] = *(const s8v*)&lsB[d][1][wn + 0][lane8];
        fb[1] = *(const s8v*)&lsB[d][1][wn + 1][lane8];
        stA(dn, 1, kn);
        asm volatile("" ::: "memory");
        __builtin_amdgcn_s_barrier();
        asm volatile("s_waitcnt lgkmcnt(0)" ::: "memory");
        __builtin_amdgcn_sched_barrier(0);
        __builtin_amdgcn_s_setprio(1);
        #pragma unroll
        for (int m = 0; m < 8; ++m) {
            acc[m][0] = __builtin_amdgcn_mfma_f32_16x16x32_bf16(fa[m], fb[0], acc[m][0], 0, 0, 0);
            acc[m][1] = __builtin_amdgcn_mfma_f32_16x16x32_bf16(fa[m], fb[1], acc[m][1], 0, 0, 0);
        }
        __builtin_amdgcn_s_setprio(0);
        asm volatile("" ::: "memory");
        __builtin_amdgcn_s_barrier();
        asm volatile("" ::: "memory");

        // ---- phase 3: ks=1, n-half 1; stage next B-ks1; force next tile's ks0 ----
        fb[0] = *(const s8v*)&lsB[d][1][wn + 2][lane8];
        fb[1] = *(const s8v*)&lsB[d][1][wn + 3][lane8];
        stB(dn, 1, kn);
        asm volatile("" ::: "memory");
        __builtin_amdgcn_s_barrier();
        asm volatile("s_waitcnt lgkmcnt(0)" ::: "memory");
        __builtin_amdgcn_sched_barrier(0);
        __builtin_amdgcn_s_setprio(1);
        #pragma unroll
        for (int m = 0; m < 8; ++m) {
            acc[m][2] = __builtin_amdgcn_mfma_f32_16x16x32_bf16(fa[m], fb[0], acc[m][2], 0, 0, 0);
            acc[m][3] = __builtin_amdgcn_mfma_f32_16x16x32_bf16(fa[m], fb[1], acc[m][3], 0, 0, 0);
        }
        __builtin_amdgcn_s_setprio(0);
        asm volatile("s_waitcnt vmcnt(4)" ::: "memory");   // forces [kt+1:A0],[kt+1:B0]
        __builtin_amdgcn_s_barrier();
        asm volatile("" ::: "memory");
    }

    asm volatile("s_waitcnt vmcnt(0)" ::: "memory");       // retire dummy staging

    // epilogue: C/D layout col=lane&15, row=(lane>>4)*4+reg
    const int rb0 = mtile * 256 + (wv >> 2) * 128 + l4 * 4;
    const int cb0 = ncol0 + (wv & 3) * 64 + l15;
    #pragma unroll
    for (int n = 0; n < 4; ++n) {
        const int col = cb0 + n * 16;
        const float bv = bias[col];
        #pragma unroll
        for (int m = 0; m < 8; ++m) {
            const int row = rb0 + m * 16;
            u16* zp = Z + (size_t)row * NG + col;
            #pragma unroll
            for (int r = 0; r < 4; ++r)
                zp[(size_t)r * NG] = f2bf(acc[m][n][r] + bv);
        }
    }
}

// ---- stats: per row (t,b): LN mu/rstd for gates 1-4 + sum_k. One wave per row. ----
__global__ __launch_bounds__(256) void stats_k(const u16* __restrict__ Z,
                                               const float* __restrict__ lng1,
                                               const float* __restrict__ lnb1,
                                               float* __restrict__ stats) {
    const int wid = threadIdx.x >> 6, lane = threadIdx.x & 63;
    const int row = blockIdx.x * 4 + wid;
    const u16* zr = Z + (size_t)row * NG + lane * 8;

    float g1v[8], b1v[8];
    #pragma unroll
    for (int j = 0; j < 8; j++) { g1v[j] = lng1[lane * 8 + j]; b1v[j] = lnb1[lane * 8 + j]; }

    float s[4], sq[4], wk = 0.f, sg1 = 0.f, sb1 = 0.f;
    #pragma unroll
    for (int g = 0; g < 4; ++g) {
        uint4 u = *(const uint4*)(zr + (g + 1) * 512);
        float f[8];
        unp8(u, f);
        float ls = 0.f, lq = 0.f;
        #pragma unroll
        for (int j = 0; j < 8; j++) { ls += f[j]; lq += f[j] * f[j]; }
        s[g] = ls; sq[g] = lq;
        if (g == 0) {
            #pragma unroll
            for (int j = 0; j < 8; j++) wk += g1v[j] * f[j];
        }
    }
    #pragma unroll
    for (int j = 0; j < 8; j++) { sg1 += g1v[j]; sb1 += b1v[j]; }

    #pragma unroll
    for (int g = 0; g < 4; ++g) { s[g] = wred64(s[g]); sq[g] = wred64(sq[g]); }
    wk = wred64(wk); sg1 = wred64(sg1); sb1 = wred64(sb1);

    if (lane == 0) {
        float* o = stats + (size_t)row * 16;
        const float inv = 1.0f / 512.0f;
        float mu1 = 0.f, rs1 = 0.f;
        #pragma unroll
        for (int g = 0; g < 4; ++g) {
            float m = s[g] * inv, e2 = sq[g] * inv;
            if (g == 0) { m *= INV_SQRT_H; e2 *= INV_SQRT_H * INV_SQRT_H; }
            const float rs = rsqrtf(fmaxf(e2 - m * m, 0.0f) + 1e-5f);
            o[1 + g] = m; o[7 + g] = rs;
            if (g == 0) { mu1 = m; rs1 = rs; }
        }
        o[12] = rs1 * (INV_SQRT_H * wk - mu1 * sg1) + sb1;
    }
}

// ---- scanA: chunk-local scan from zero state. One thread per (chunk,b,h). ----
__global__ __launch_bounds__(128) void scanA_k(const u16* __restrict__ Z,
                                               const float* __restrict__ stats,
                                               const float* __restrict__ lngl,
                                               const float* __restrict__ lnbl,
                                               u16* __restrict__ nbuf,
                                               u16* __restrict__ pbuf,
                                               float* __restrict__ sumP,
                                               float* __restrict__ sumC,
                                               float* __restrict__ sumN) {
    const int b = blockIdx.y, chunk = blockIdx.z;
    const int h = blockIdx.x * 128 + threadIdx.x;
    __shared__ float sst[CH][16];
    for (int i = threadIdx.x; i < CH * 16; i += 128) {
        const int tc = i >> 4, j = i & 15;
        sst[tc][j] = stats[(size_t)((chunk * CH + tc) * 64 + b) * 16 + j];
    }
    float gg[4], gb[4];
    #pragma unroll
    for (int g = 0; g < 4; ++g) {
        gg[g] = lngl[(g + 1) * 512 + h];
        gb[g] = lnbl[(g + 1) * 512 + h];
    }
    __syncthreads();

    float c = 0.f, n = 0.f, P = 1.f;
    #pragma unroll 4
    for (int tc = 0; tc < CH; ++tc) {
        const int r = (chunk * CH + tc) * 64 + b;
        const u16* zr = Z + (size_t)r * NG + h;
        const float z1 = bu2f(zr[512]);
        const float z2 = bu2f(zr[1024]);
        const float z3 = bu2f(zr[1536]);
        const float z4 = bu2f(zr[2048]);
        const float kk = (z1 * INV_SQRT_H - sst[tc][1]) * sst[tc][7] * gg[0] + gb[0];
        const float vv = (z2 - sst[tc][2]) * sst[tc][8]  * gg[1] + gb[1];
        const float ii = sigm((z3 - sst[tc][3]) * sst[tc][9]  * gg[2] + gb[2]);
        const float ff = sigm((z4 - sst[tc][4]) * sst[tc][10] * gg[3] + gb[3]);
        c = ff * c + ii * (sst[tc][12] * vv);
        n = ff * n + ii * kk;
        P *= ff;
        nbuf[(size_t)r * 512 + h] = f2bf(n);
        pbuf[(size_t)r * 512 + h] = f2bf(P);
    }
    const size_t idx = ((size_t)chunk << 15) + (b << 9) + h;
    sumP[idx] = P; sumC[idx] = c; sumN[idx] = n;
}

// ---- scanB: exact fp32 combine across chunks; emits per-chunk incoming n0. ----
__global__ __launch_bounds__(256) void scanB_k(const float* __restrict__ sumP,
                                               const float* __restrict__ sumC,
                                               const float* __restrict__ sumN,
                                               float* __restrict__ n0buf,
                                               float* __restrict__ cstate,
                                               float* __restrict__ nstate,
                                               float* __restrict__ finals,
                                               int t0, int NC, int l) {
    const int idx = blockIdx.x * 256 + threadIdx.x;   // 0..32767
    float c, n;
    if (t0 == 0) { c = 0.f; n = 0.f; }
    else { c = cstate[idx]; n = nstate[idx]; }
    for (int ch = 0; ch < NC; ++ch) {
        const size_t o = ((size_t)ch << 15) + idx;
        n0buf[o] = n;
        const float P = sumP[o];
        c = sumC[o] + P * c;
        n = sumN[o] + P * n;
    }
    if (t0 + NC * CH == S_) {
        const int b = idx >> 9, h = idx & 511;
        const size_t so = ((size_t)l * B_ + b) * H_ + h;
        finals[(size_t)L_ * B_ * H_ + so] = c;       // c final (exact fp32 combine)
        finals[(size_t)2 * L_ * B_ * H_ + so] = n;   // n final
    } else {
        cstate[idx] = c; nstate[idx] = n;
    }
}

// ---- normh: one wave per (t,b) row. Inline stats for gates 0,5. ----
__global__ __launch_bounds__(256) void normh_k(const u16* __restrict__ Z,
                                               const u16* __restrict__ nbuf,
                                               const u16* __restrict__ pbuf,
                                               const float* __restrict__ n0buf,
                                               const float* __restrict__ lngl,
                                               const float* __restrict__ lnbl,
                                               float* __restrict__ hbuf,
                                               u16* __restrict__ aoutB,  // null for l==3
                                               float* __restrict__ outp, // null for l<3
                                               float* __restrict__ finals,
                                               int t0, int l) {
    const int wid = threadIdx.x >> 6, lane = threadIdx.x & 63;
    const int r = blockIdx.x * 4 + wid;
    const int h0 = lane * 8;

    float nl[8], pv[8];
    unp8(*(const uint4*)(nbuf + (size_t)r * 512 + h0), nl);
    unp8(*(const uint4*)(pbuf + (size_t)r * 512 + h0), pv);
    const float* n0r = n0buf + ((size_t)(r >> 10) << 15) + ((size_t)(r & 63) << 9) + h0;
    const float4 na = *(const float4*)(n0r);
    const float4 nb = *(const float4*)(n0r + 4);
    const float n0v[8] = {na.x, na.y, na.z, na.w, nb.x, nb.y, nb.z, nb.w};

    const u16* zr = Z + (size_t)r * NG;
    float z0[8], z5[8];
    unp8(*(const uint4*)(zr + h0), z0);
    unp8(*(const uint4*)(zr + 2560 + h0), z5);

    // combined reductions: ||n||^2 and gate-0/5 LN stats
    float nsq = 0.f, s0 = 0.f, q0 = 0.f, s5 = 0.f, q5 = 0.f;
    float nv[8];
    #pragma unroll
    for (int j = 0; j < 8; j++) {
        nv[j] = fmaf(pv[j], n0v[j], nl[j]);
        nsq += nv[j] * nv[j];
        s0 += z0[j]; q0 += z0[j] * z0[j];
        s5 += z5[j]; q5 += z5[j] * z5[j];
    }
    nsq = wred64(nsq);
    s0 = wred64(s0); q0 = wred64(q0);
    s5 = wred64(s5); q5 = wred64(q5);
    const float rinv = 1.0f / (sqrtf(nsq) + 1e-8f);
    const float inv = 1.0f / 512.0f;
    const float mu0 = s0 * inv, mu5 = s5 * inv;
    const float rs0 = rsqrtf(fmaxf(q0 * inv - mu0 * mu0, 0.0f) + 1e-5f);
    const float rs5 = rsqrtf(fmaxf(q5 * inv - mu5 * mu5, 0.0f) + 1e-5f);

    float g0[8], b0[8], g5[8], b5[8];
    #pragma unroll
    for (int j = 0; j < 8; j++) {
        g0[j] = lngl[h0 + j];        b0[j] = lnbl[h0 + j];
        g5[j] = lngl[2560 + h0 + j]; b5[j] = lnbl[2560 + h0 + j];
    }

    const int tl = r >> 6, b = r & 63;
    const int gr = t0 + tl;
    const size_t grow = (((size_t)gr * 64 + b) * 512) + h0;

    float hv[8];
    #pragma unroll
    for (int j = 0; j < 8; j++) {
        const float q  = (z0[j] - mu0) * rs0 * g0[j] + b0[j];
        const float oo = sigm((z5[j] - mu5) * rs5 * g5[j] + b5[j]);
        hv[j] = oo * tanhf_(q * nv[j] * rinv);
    }
    if (l > 0) {
        #pragma unroll
        for (int j = 0; j < 8; j++) hv[j] += hbuf[grow + j];
    }
    if (outp) {
        #pragma unroll
        for (int j = 0; j < 8; j++) outp[grow + j] = hv[j];
    } else {
        #pragma unroll
        for (int j = 0; j < 8; j++) hbuf[grow + j] = hv[j];
    }
    if (aoutB) *(uint4*)(aoutB + grow) = pck8(hv);

    if (gr == S_ - 1) {
        const size_t so = (((size_t)l * B_ + b) * 512) + h0;
        #pragma unroll
        for (int j = 0; j < 8; j++) finals[so + j] = hv[j];
    }
}

extern "C" void kernel_launch(void* const* d_in, const int* in_sizes, int n_in,
                              void* d_out, int out_size, void* d_ws, size_t ws_size,
                              hipStream_t stream) {
    const float* x   = (const float*)d_in[0];
    const float* W   = (const float*)d_in[1];
    const float* bia = (const float*)d_in[2];
    const float* lng = (const float*)d_in[3];
    const float* lnb = (const float*)d_in[4];
    float* out = (float*)d_out;

    const size_t WT_B = (size_t)L_ * 6 * H_ * F_ * 2;   // 12.58 MB
    const size_t A_B  = (size_t)RALL * F_ * 2;          // 16.78 MB
    const size_t ST_B = (size_t)RALL * 16 * 4;          // 1.05 MB
    const size_t CS_B = (size_t)B_ * H_ * 4;            // 128 KB
    const size_t HB_B = (size_t)RALL * H_ * 4;          // 33.55 MB
    auto zB  = [](int T) { return (size_t)T * B_ * NG * 2; };
    auto nB  = [](int T) { return (size_t)T * B_ * H_ * 2; };
    auto cxB = [](int T) { return (size_t)(T / CH) * B_ * H_ * 4; };
    const size_t base = WT_B + A_B + ST_B + 2 * CS_B + HB_B + 32768;

    int T = 16;
    const int cand[3] = {256, 64, 16};
    for (int i = 0; i < 3; i++) {
        const int Tc = cand[i];
        if (ws_size >= base + zB(Tc) + 2 * nB(Tc) + 4 * cxB(Tc)) { T = Tc; break; }
    }
    const int NC = T / CH;

    char* ws = (char*)d_ws;
    size_t off = 0;
    auto take = [&](size_t nb) { size_t o = off; off += (nb + 255) & ~(size_t)255; return o; };
    u16*   WT    = (u16*)  (ws + take(WT_B));
    u16*   Abf   = (u16*)  (ws + take(A_B));
    float* stats = (float*)(ws + take(ST_B));
    float* cs    = (float*)(ws + take(CS_B));
    float* ns    = (float*)(ws + take(CS_B));
    float* hbuf  = (float*)(ws + take(HB_B));
    u16*   zb    = (u16*)  (ws + take(zB(T)));
    u16*   nbuf  = (u16*)  (ws + take(nB(T)));
    u16*   pbuf  = (u16*)  (ws + take(nB(T)));
    float* sumP  = (float*)(ws + take(cxB(T)));
    float* sumC  = (float*)(ws + take(cxB(T)));
    float* sumN  = (float*)(ws + take(cxB(T)));
    float* n0buf = (float*)(ws + take(cxB(T)));

    convw_k<<<dim3(16, 16, 24), dim3(32, 8), 0, stream>>>(W, WT);
    convx_k<<<dim3(RALL * F_ / 4 / 256), dim3(256), 0, stream>>>(x, Abf);

    float* finals = out + (size_t)S_ * B_ * H_;
    for (int l = 0; l < L_; ++l) {
        const u16*   WTl   = WT  + (size_t)l * 6 * H_ * F_;
        const float* biasl = bia + (size_t)l * NG;
        const float* lngl  = lng + (size_t)l * 6 * H_;
        const float* lnbl  = lnb + (size_t)l * 6 * H_;
        for (int j = 0; j < S_ / T; ++j) {
            const int t0 = j * T, arow0 = t0 * B_;
            const int rows = T * B_;
            gemm_k<<<dim3(12 * (rows / 256)), dim3(512), 0, stream>>>(Abf, WTl, zb, biasl, arow0);
            stats_k<<<dim3(rows / 4), dim3(256), 0, stream>>>(zb, lngl + H_, lnbl + H_, stats);
            scanA_k<<<dim3(4, B_, NC), dim3(128), 0, stream>>>(zb, stats, lngl, lnbl,
                                                               nbuf, pbuf, sumP, sumC, sumN);
            scanB_k<<<dim3(128), dim3(256), 0, stream>>>(sumP, sumC, sumN, n0buf,
                                                         cs, ns, finals, t0, NC, l);
            normh_k<<<dim3(rows / 4), dim3(256), 0, stream>>>(zb, nbuf, pbuf, n0buf,
                                                              lngl, lnbl, hbuf,
                                                              (l < 3) ? Abf : (u16*)nullptr,
                                                              (l == 3) ? out : (float*)nullptr,
                                                              finals, t0, l);
        }
    }
}